// Round 1
// baseline (290.525 us; speedup 1.0000x reference)
//
#include <hip/hip_runtime.h>

#define N_WORDS 16384
#define TSTEPS 16
#define NCHARS 128
#define HIDDEN 128

typedef float f32x4 __attribute__((ext_vector_type(4)));
typedef short s16x4 __attribute__((ext_vector_type(4)));
typedef short s16x8 __attribute__((ext_vector_type(8)));
typedef int   i32x4 __attribute__((ext_vector_type(4)));

// fp32 -> bf16 round-to-nearest-even (values are finite, no NaN handling needed)
static __device__ __forceinline__ short f2bf(float f) {
  unsigned u = __builtin_bit_cast(unsigned, f);
  u += 0x7FFFu + ((u >> 16) & 1u);
  return (short)(u >> 16);
}
static __device__ __forceinline__ float fast_sigmoid(float x) {
  float e = __builtin_amdgcn_exp2f(x * -1.44269504089f);   // e^-x
  return __builtin_amdgcn_rcpf(1.0f + e);
}
static __device__ __forceinline__ float fast_tanh(float x) {
  float e = __builtin_amdgcn_exp2f(x * 2.88539008178f);    // e^{2x}
  return 1.0f - 2.0f * __builtin_amdgcn_rcpf(1.0f + e);
}

// ---------------------------------------------------------------------------
// Kernel 1: one wave per (n,t) row; find the one-hot index.
// Lane reads float2 -> 512B per wave, fully coalesced. Writes idx transposed
// [t][n] so the LSTM kernel can int4-load 4 consecutive words.
// ---------------------------------------------------------------------------
__global__ __launch_bounds__(256) void k_extract(const float* __restrict__ x,
                                                 int* __restrict__ idx_t) {
  const int wave = (int)((blockIdx.x * 256u + threadIdx.x) >> 6);  // n*16 + t
  const int lane = threadIdx.x & 63;
  const float2 v = *(const float2*)(x + (size_t)wave * NCHARS + lane * 2);
  unsigned long long m0 = __ballot(v.x > 0.5f);
  unsigned long long m1 = __ballot(v.y > 0.5f);
  int c;
  if (m0) c = (__ffsll(m0) - 1) * 2;
  else    c = (__ffsll(m1) - 1) * 2 + 1;
  if (lane == 0) {
    const int n = wave >> 4, t = wave & 15;
    idx_t[t * N_WORDS + n] = c;
  }
}

// ---------------------------------------------------------------------------
// Kernel 2: precompute WT_ihb[dir][char][half][wave][u] as float4
//   half 0 -> (i[u], i[u+16], f[u], f[u+16]) ; half 1 -> (g,..., o,...)
// where unit = wave*32 + {u | u+16}; includes b_ih + b_hh.
// One float4 per thread, 32768 threads.
// ---------------------------------------------------------------------------
__global__ __launch_bounds__(256) void k_prep(
    const float* __restrict__ Wf, const float* __restrict__ bif, const float* __restrict__ bhf,
    const float* __restrict__ Wb, const float* __restrict__ bib, const float* __restrict__ bhb,
    f32x4* __restrict__ outp) {
  const int gid = blockIdx.x * 256 + threadIdx.x;     // [0, 32768)
  const int u    = gid & 15;
  const int wv   = (gid >> 4) & 3;
  const int half = (gid >> 6) & 1;
  const int c    = (gid >> 7) & 127;
  const int d    = gid >> 14;
  const float* W  = d ? Wb : Wf;
  const float* bi = d ? bib : bif;
  const float* bh = d ? bhb : bhf;
  const int g0 = half * 2 * HIDDEN;     // first gate-type row base
  const int g1 = g0 + HIDDEN;
  const int ua = wv * 32 + u, ub = ua + 16;
  f32x4 v;
  v[0] = W[(g0 + ua) * NCHARS + c] + bi[g0 + ua] + bh[g0 + ua];
  v[1] = W[(g0 + ub) * NCHARS + c] + bi[g0 + ub] + bh[g0 + ub];
  v[2] = W[(g1 + ua) * NCHARS + c] + bi[g1 + ua] + bh[g1 + ua];
  v[3] = W[(g1 + ub) * NCHARS + c] + bi[g1 + ub] + bh[g1 + ub];
  outp[gid] = v;
}

// ---------------------------------------------------------------------------
// Kernel 3: the recurrence. Block = 4 waves = 16 words, one direction.
// Wave w owns hidden units [32w, 32w+32): 8 MFMA N-tiles (4 gate types x 2),
// W_hh held as bf16 B-fragments in 128 VGPRs. h ping-pongs through LDS in a
// permuted layout so an A-fragment is ONE aligned ds_read_b128.
//   A-frag (16x16x32): lane l holds A[m=l&15][k], k = 4*(l>>4)+j (j<4),
//                      k = 16+4*(l>>4)+(j-4) (j>=4)   [two stacked K=16 halves]
//   C/D: lane l, reg r -> row m=(l>>4)*4+r, col n=l&15
// LDS row stride 136 shorts (16B-aligned rows, balanced banks).
// ---------------------------------------------------------------------------
#define HSTRIDE 136

__global__ __launch_bounds__(256) void k_lstm(
    const int* __restrict__ lengths,
    const float* __restrict__ Whh_f, const float* __restrict__ Whh_b,
    const f32x4* __restrict__ wihp, const int* __restrict__ idx_t,
    float* __restrict__ out) {
  const int dir  = blockIdx.x >> 10;
  const int tile = blockIdx.x & 1023;
  const int n0   = tile << 4;
  const int widx = threadIdx.x >> 6;
  const int lane = threadIdx.x & 63;
  const int l15  = lane & 15;
  const int q    = lane >> 4;
  const float* __restrict__ Whh = dir ? Whh_b : Whh_f;

  // --- load W_hh into bf16 B-fragments: B[k][n] = W_hh[n][k] ---
  s16x8 Bf[4][2][4];   // [gate_type][tile16][k_tile]
#pragma unroll
  for (int gt = 0; gt < 4; ++gt)
#pragma unroll
    for (int ti = 0; ti < 2; ++ti) {
      const int g = gt * 128 + widx * 32 + ti * 16 + l15;
#pragma unroll
      for (int kt = 0; kt < 4; ++kt) {
        const int k0 = kt * 32 + q * 4;
        f32x4 lo = *(const f32x4*)(Whh + g * 128 + k0);
        f32x4 hi = *(const f32x4*)(Whh + g * 128 + k0 + 16);
        s16x8 f;
        f[0] = f2bf(lo[0]); f[1] = f2bf(lo[1]); f[2] = f2bf(lo[2]); f[3] = f2bf(lo[3]);
        f[4] = f2bf(hi[0]); f[5] = f2bf(hi[1]); f[6] = f2bf(hi[2]); f[7] = f2bf(hi[3]);
        Bf[gt][ti][kt] = f;
      }
    }

  __shared__ short hbuf[2][16 * HSTRIDE];
  for (int i = threadIdx.x; i < 16 * HSTRIDE; i += 256) hbuf[0][i] = 0;

  const i32x4 lenv = *(const i32x4*)(lengths + n0 + q * 4);

  f32x4 c0 = (f32x4)0.0f, c1 = (f32x4)0.0f;   // cell state, tiles 0/1
  f32x4 h0 = (f32x4)0.0f, h1 = (f32x4)0.0f;   // hidden state (fp32 master)

  __syncthreads();

  for (int t = 0; t < TSTEPS; ++t) {
    const short* __restrict__ hr = hbuf[t & 1];
    short* __restrict__ hw = hbuf[(t & 1) ^ 1];
    const int t_eff = dir ? (TSTEPS - 1 - t) : t;

    // char indices for this lane's 4 accumulator rows (words n0+4q..+3)
    const i32x4 cc = *(const i32x4*)(idx_t + t_eff * N_WORDS + n0 + q * 4);

    // xproj gathers (issued early; overlap MFMA)
    f32x4 xpA[4], xpB[4];
#pragma unroll
    for (int r = 0; r < 4; ++r) {
      const f32x4* base = wihp + ((size_t)dir * 16384 + (size_t)cc[r] * 128 + widx * 16 + l15);
      xpA[r] = base[0];     // (i,u) (i,u+16) (f,u) (f,u+16)
      xpB[r] = base[64];    // (g,u) (g,u+16) (o,u) (o,u+16)
    }

    f32x4 acc[4][2];
#pragma unroll
    for (int gt = 0; gt < 4; ++gt)
#pragma unroll
      for (int ti = 0; ti < 2; ++ti) acc[gt][ti] = (f32x4)0.0f;

#pragma unroll
    for (int kt = 0; kt < 4; ++kt) {
      const s16x8 a = *(const s16x8*)(hr + l15 * HSTRIDE + kt * 32 + q * 8);
#pragma unroll
      for (int gt = 0; gt < 4; ++gt)
#pragma unroll
        for (int ti = 0; ti < 2; ++ti)
          acc[gt][ti] = __builtin_amdgcn_mfma_f32_16x16x32_bf16(
              a, Bf[gt][ti][kt], acc[gt][ti], 0, 0, 0);
    }

    // epilogue: activations + state update (fp32), masked freeze
#pragma unroll
    for (int r = 0; r < 4; ++r) {
      const bool mk = (t_eff < lenv[r]);
#pragma unroll
      for (int ti = 0; ti < 2; ++ti) {
        const float xi = ti ? xpA[r][1] : xpA[r][0];
        const float xf = ti ? xpA[r][3] : xpA[r][2];
        const float xg = ti ? xpB[r][1] : xpB[r][0];
        const float xo = ti ? xpB[r][3] : xpB[r][2];
        const float gi = fast_sigmoid(acc[0][ti][r] + xi);
        const float gf = fast_sigmoid(acc[1][ti][r] + xf);
        const float gg = fast_tanh   (acc[2][ti][r] + xg);
        const float go = fast_sigmoid(acc[3][ti][r] + xo);
        float cs = ti ? c1[r] : c0[r];
        float hs = ti ? h1[r] : h0[r];
        const float cn = gf * cs + gi * gg;
        const float hn = go * fast_tanh(cn);
        cs = mk ? cn : cs;
        hs = mk ? hn : hs;
        if (ti) { c1[r] = cs; h1[r] = hs; } else { c0[r] = cs; h0[r] = hs; }
        // permuted store: unit = widx*32 + ti*16 + l15  ->
        // pos = widx*32 + (l15>>2)*8 + ti*4 + (l15&3)
        hw[(4 * q + r) * HSTRIDE + widx * 32 + (l15 >> 2) * 8 + ti * 4 + (l15 & 3)] = f2bf(hs);
      }
    }
    __syncthreads();
  }

  // final hidden -> out[n][dir*128 + unit]
#pragma unroll
  for (int r = 0; r < 4; ++r) {
    const int n = n0 + 4 * q + r;
    out[(size_t)n * 256 + dir * 128 + widx * 32 + l15]      = h0[r];
    out[(size_t)n * 256 + dir * 128 + widx * 32 + 16 + l15] = h1[r];
  }
}

// ---------------------------------------------------------------------------
extern "C" void kernel_launch(void* const* d_in, const int* in_sizes, int n_in,
                              void* d_out, int out_size, void* d_ws, size_t ws_size,
                              hipStream_t stream) {
  const float* x      = (const float*)d_in[0];
  const int*   lens   = (const int*)d_in[1];
  const float* W_ih_f = (const float*)d_in[2];
  const float* W_hh_f = (const float*)d_in[3];
  const float* b_ih_f = (const float*)d_in[4];
  const float* b_hh_f = (const float*)d_in[5];
  const float* W_ih_b = (const float*)d_in[6];
  const float* W_hh_b = (const float*)d_in[7];
  const float* b_ih_b = (const float*)d_in[8];
  const float* b_hh_b = (const float*)d_in[9];
  float* out = (float*)d_out;

  int*   idx_t = (int*)d_ws;                             // 16*16384*4 = 1 MB
  f32x4* wihp  = (f32x4*)((char*)d_ws + (1u << 20));     // 32768*16  = 512 KB

  hipLaunchKernelGGL(k_extract, dim3((N_WORDS * TSTEPS) / 4), dim3(256), 0, stream,
                     x, idx_t);
  hipLaunchKernelGGL(k_prep, dim3(32768 / 256), dim3(256), 0, stream,
                     W_ih_f, b_ih_f, b_hh_f, W_ih_b, b_ih_b, b_hh_b, wihp);
  hipLaunchKernelGGL(k_lstm, dim3(2048), dim3(256), 0, stream,
                     lens, W_hh_f, W_hh_b, wihp, idx_t, out);
}

// Round 2
// 238.231 us; speedup vs baseline: 1.2195x; 1.2195x over previous
//
#include <hip/hip_runtime.h>

#define N_WORDS 16384
#define TSTEPS 16
#define NCHARS 128
#define HIDDEN 128
#define HSTRIDE 136   // shorts per LDS row: 16B-aligned, bank-staggered

typedef float f32x4 __attribute__((ext_vector_type(4)));
typedef short s16x8 __attribute__((ext_vector_type(8)));
typedef int   i32x4 __attribute__((ext_vector_type(4)));

// fp32 -> bf16 round-to-nearest-even
static __device__ __forceinline__ short f2bf(float f) {
  unsigned u = __builtin_bit_cast(unsigned, f);
  u += 0x7FFFu + ((u >> 16) & 1u);
  return (short)(u >> 16);
}
static __device__ __forceinline__ float fast_sigmoid(float x) {
  float e = __builtin_amdgcn_exp2f(x * -1.44269504089f);   // e^-x
  return __builtin_amdgcn_rcpf(1.0f + e);
}
static __device__ __forceinline__ float fast_tanh(float x) {
  float e = __builtin_amdgcn_exp2f(x * 2.88539008178f);    // e^{2x}
  return 1.0f - 2.0f * __builtin_amdgcn_rcpf(1.0f + e);
}

// ---------------------------------------------------------------------------
// Kernel 1: one-hot -> char index. 2 rows per wave (float4/lane).
// Writes idx transposed [t][n] for int4 loads in the LSTM kernel.
// ---------------------------------------------------------------------------
__global__ __launch_bounds__(256) void k_extract(const float* __restrict__ x,
                                                 int* __restrict__ idx_t) {
  const int wpair = blockIdx.x * 4 + (threadIdx.x >> 6);
  const int lane  = threadIdx.x & 63;
  const int half  = lane >> 5, sub = lane & 31;
  const long row  = (long)wpair * 2 + half;           // row = n*16 + t
  const f32x4 v = *(const f32x4*)(x + row * NCHARS + sub * 4);
  int loc = -1;
  loc = (v[0] > 0.5f) ? 0 : loc;
  loc = (v[1] > 0.5f) ? 1 : loc;
  loc = (v[2] > 0.5f) ? 2 : loc;
  loc = (v[3] > 0.5f) ? 3 : loc;
  const unsigned long long ball = __ballot(loc >= 0);
  const int w0 = __ffsll(ball & 0xffffffffull) - 1;
  const int w1 = __ffsll(ball >> 32) - 1 + 32;
  const int myv = sub * 4 + loc;
  const int c0 = __shfl(myv, w0);
  const int c1 = __shfl(myv, w1);
  if (lane == 0) {
    const int r0 = wpair * 2, r1 = r0 + 1;
    idx_t[(r0 & 15) * N_WORDS + (r0 >> 4)] = c0;
    idx_t[(r1 & 15) * N_WORDS + (r1 >> 4)] = c1;
  }
}

// ---------------------------------------------------------------------------
// Kernel 2: xproj table  xp[dir][char][unit] = float4 over gates (i,f,g,o),
// includes b_ih + b_hh. One float4 per thread, 32768 threads.
// ---------------------------------------------------------------------------
__global__ __launch_bounds__(256) void k_prep(
    const float* __restrict__ Wf, const float* __restrict__ bif, const float* __restrict__ bhf,
    const float* __restrict__ Wb, const float* __restrict__ bib, const float* __restrict__ bhb,
    f32x4* __restrict__ outp) {
  const int gid = blockIdx.x * 256 + threadIdx.x;   // [0, 32768)
  const int u = gid & 127;
  const int c = (gid >> 7) & 127;
  const int d = gid >> 14;
  const float* W  = d ? Wb : Wf;
  const float* bi = d ? bib : bif;
  const float* bh = d ? bhb : bhf;
  f32x4 v;
#pragma unroll
  for (int g = 0; g < 4; ++g) {
    const int gr = g * HIDDEN + u;
    v[g] = W[gr * NCHARS + c] + bi[gr] + bh[gr];
  }
  outp[gid] = v;
}

// ---------------------------------------------------------------------------
// Kernel 3: recurrence. Block = 1024 threads = 16 waves, 32 words, one dir.
// Wave (mg,ug): M-group mg (16 words), units [ug*16, ug*16+16).
//   B-frags (bf16 W_hh^T slice) : 16 x s16x8 = 64 VGPRs, resident
//   per step: 4 ds_read_b128 (A), 16 MFMA 16x16x32_bf16, 4 cell updates/thread
// Forced VGPR<=128 (1024-thr block) -> 4 waves/SIMD resident.
// h ping-pongs through LDS in the permuted layout so an A-fragment is one
// aligned ds_read_b128:
//   A-frag: lane l reads k = kt*32 + (l>>4)*4 + j (j<4), +16 for j>=4
//   C/D   : lane l, reg r -> row m=(l>>4)*4+r, col n=l&15
// ---------------------------------------------------------------------------
__global__ __launch_bounds__(1024) void k_lstm(
    const int* __restrict__ lengths,
    const float* __restrict__ Whh_f, const float* __restrict__ Whh_b,
    const f32x4* __restrict__ xproj, const int* __restrict__ idx_t,
    float* __restrict__ out) {
  const int dir = blockIdx.x >> 9;
  const int n0  = (blockIdx.x & 511) << 5;        // 32 words per block
  const int wi  = threadIdx.x >> 6;
  const int ug  = wi & 7, mg = wi >> 3;
  const int lane = threadIdx.x & 63;
  const int l15 = lane & 15, q = lane >> 4;
  const float* __restrict__ Whh = dir ? Whh_b : Whh_f;

  // B[k][n] = W_hh[n][k], n = gate-row g*128 + ug*16 + l15
  s16x8 Bf[4][4];
#pragma unroll
  for (int g = 0; g < 4; ++g) {
    const int row = g * HIDDEN + ug * 16 + l15;
#pragma unroll
    for (int kt = 0; kt < 4; ++kt) {
      const int k0 = kt * 32 + q * 4;
      const f32x4 lo = *(const f32x4*)(Whh + row * HIDDEN + k0);
      const f32x4 hi = *(const f32x4*)(Whh + row * HIDDEN + k0 + 16);
      s16x8 f;
      f[0] = f2bf(lo[0]); f[1] = f2bf(lo[1]); f[2] = f2bf(lo[2]); f[3] = f2bf(lo[3]);
      f[4] = f2bf(hi[0]); f[5] = f2bf(hi[1]); f[6] = f2bf(hi[2]); f[7] = f2bf(hi[3]);
      Bf[g][kt] = f;
    }
  }

  __shared__ short hbuf[2][32 * HSTRIDE];
  for (int i = threadIdx.x; i < 32 * HSTRIDE; i += 1024) hbuf[0][i] = 0;

  const int wbase = n0 + mg * 16 + q * 4;          // this thread's 4 words
  const i32x4 lenv = *(const i32x4*)(lengths + wbase);

  f32x4 h = (f32x4)0.0f, c = (f32x4)0.0f;
  // permuted store position for unit u = ug*16 + l15
  const int pos = (ug >> 1) * 32 + (l15 >> 2) * 8 + (ug & 1) * 4 + (l15 & 3);

  __syncthreads();

  for (int t = 0; t < TSTEPS; ++t) {
    const short* __restrict__ hr = hbuf[t & 1] + (mg * 16 + l15) * HSTRIDE;
    short* __restrict__ hw = hbuf[(t & 1) ^ 1];
    const int t_eff = dir ? (TSTEPS - 1 - t) : t;

    const i32x4 cc = *(const i32x4*)(idx_t + t_eff * N_WORDS + wbase);

    // xproj gathers: one float4 (4 gates) per word; issued before MFMA
    f32x4 xpv[4];
#pragma unroll
    for (int r = 0; r < 4; ++r)
      xpv[r] = xproj[(dir << 14) + (cc[r] << 7) + ug * 16 + l15];

    f32x4 acc[4] = {(f32x4)0.0f, (f32x4)0.0f, (f32x4)0.0f, (f32x4)0.0f};
#pragma unroll
    for (int kt = 0; kt < 4; ++kt) {
      const s16x8 a = *(const s16x8*)(hr + kt * 32 + q * 8);
#pragma unroll
      for (int g = 0; g < 4; ++g)
        acc[g] = __builtin_amdgcn_mfma_f32_16x16x32_bf16(a, Bf[g][kt], acc[g], 0, 0, 0);
    }

#pragma unroll
    for (int r = 0; r < 4; ++r) {
      const bool mk = (t_eff < lenv[r]);
      const float gi = fast_sigmoid(acc[0][r] + xpv[r][0]);
      const float gf = fast_sigmoid(acc[1][r] + xpv[r][1]);
      const float gg = fast_tanh   (acc[2][r] + xpv[r][2]);
      const float go = fast_sigmoid(acc[3][r] + xpv[r][3]);
      const float cn = gf * c[r] + gi * gg;
      const float hn = go * fast_tanh(cn);
      c[r] = mk ? cn : c[r];
      h[r] = mk ? hn : h[r];
      hw[(mg * 16 + q * 4 + r) * HSTRIDE + pos] = f2bf(h[r]);
    }
    __syncthreads();
  }

#pragma unroll
  for (int r = 0; r < 4; ++r)
    out[(size_t)(wbase + r) * 256 + dir * HIDDEN + ug * 16 + l15] = h[r];
}

// ---------------------------------------------------------------------------
extern "C" void kernel_launch(void* const* d_in, const int* in_sizes, int n_in,
                              void* d_out, int out_size, void* d_ws, size_t ws_size,
                              hipStream_t stream) {
  const float* x      = (const float*)d_in[0];
  const int*   lens   = (const int*)d_in[1];
  const float* W_ih_f = (const float*)d_in[2];
  const float* W_hh_f = (const float*)d_in[3];
  const float* b_ih_f = (const float*)d_in[4];
  const float* b_hh_f = (const float*)d_in[5];
  const float* W_ih_b = (const float*)d_in[6];
  const float* W_hh_b = (const float*)d_in[7];
  const float* b_ih_b = (const float*)d_in[8];
  const float* b_hh_b = (const float*)d_in[9];
  float* out = (float*)d_out;

  int*   idx_t = (int*)d_ws;                             // 16*16384*4 = 1 MB
  f32x4* xproj = (f32x4*)((char*)d_ws + (1u << 20));     // 32768*16  = 512 KB

  hipLaunchKernelGGL(k_extract, dim3((N_WORDS * TSTEPS) / 8), dim3(256), 0, stream,
                     x, idx_t);
  hipLaunchKernelGGL(k_prep, dim3(32768 / 256), dim3(256), 0, stream,
                     W_ih_f, b_ih_f, b_hh_f, W_ih_b, b_ih_b, b_hh_b, xproj);
  hipLaunchKernelGGL(k_lstm, dim3(1024), dim3(1024), 0, stream,
                     lens, W_hh_f, W_hh_b, xproj, idx_t, out);
}

// Round 4
// 217.729 us; speedup vs baseline: 1.3343x; 1.0942x over previous
//
#include <hip/hip_runtime.h>

#define N_WORDS 16384
#define TSTEPS 16
#define NCHARS 128
#define HIDDEN 128
#define HSTRIDE 136   // shorts per LDS row: 16B-aligned, bank-staggered

typedef float f32x4 __attribute__((ext_vector_type(4)));
typedef short s16x8 __attribute__((ext_vector_type(8)));
typedef int   i32x4 __attribute__((ext_vector_type(4)));
typedef unsigned int u32;

// ws layout (bytes)
#define WS_IDX   0                         // 262144: idx_p bytes [t][slot]  (slot-indexed!)
#define WS_XPROJ (256 * 1024)              // 524288: xproj f32x4 [dir][char][unit]
#define WS_PERM  (WS_XPROJ + 512 * 1024)   // 65536 : perm  (slot -> word id)
#define WS_LEN   (WS_PERM + 64 * 1024)     // 65536 : len_perm (slot -> length)
#define WS_INV   (WS_LEN + 64 * 1024)      // 65536 : slot_of (word id -> slot)
#define WS_CTRL  (WS_INV + 64 * 1024)      // ghist[16] | gbase[16] | gcursor[16]

// fp32 -> bf16 round-to-nearest-even
static __device__ __forceinline__ short f2bf(float f) {
  unsigned u = __builtin_bit_cast(unsigned, f);
  u += 0x7FFFu + ((u >> 16) & 1u);
  return (short)(u >> 16);
}
static __device__ __forceinline__ float fast_sigmoid(float x) {
  float e = __builtin_amdgcn_exp2f(x * -1.44269504089f);   // e^-x
  return __builtin_amdgcn_rcpf(1.0f + e);
}
static __device__ __forceinline__ float fast_tanh(float x) {
  float e = __builtin_amdgcn_exp2f(x * 2.88539008178f);    // e^{2x}
  return 1.0f - 2.0f * __builtin_amdgcn_rcpf(1.0f + e);
}

// ---------------------------------------------------------------------------
// counting sort by length: hist -> scan -> place (+ inverse perm)
// ---------------------------------------------------------------------------
__global__ __launch_bounds__(256) void k_hist(const int* __restrict__ lengths,
                                              int* __restrict__ ghist) {
  __shared__ int lh[16];
  if (threadIdx.x < 16) lh[threadIdx.x] = 0;
  __syncthreads();
  const int len = lengths[blockIdx.x * 256 + threadIdx.x];
  atomicAdd(&lh[len - 1], 1);
  __syncthreads();
  if (threadIdx.x < 16) atomicAdd(&ghist[threadIdx.x], lh[threadIdx.x]);
}

__global__ void k_scan(const int* __restrict__ ghist, int* __restrict__ gbase) {
  if (threadIdx.x == 0 && blockIdx.x == 0) {
    int s = 0;
    for (int b = 0; b < 16; ++b) { gbase[b] = s; s += ghist[b]; }
  }
}

__global__ __launch_bounds__(256) void k_place(const int* __restrict__ lengths,
                                               const int* __restrict__ gbase,
                                               int* __restrict__ gcursor,
                                               int* __restrict__ perm,
                                               int* __restrict__ len_perm,
                                               int* __restrict__ slot_of) {
  __shared__ int wcnt[4][16];
  __shared__ int bbase[16];
  const int tid = threadIdx.x, w = tid >> 6, lane = tid & 63;
  const int gid = blockIdx.x * 256 + tid;
  const int len = lengths[gid], bin = len - 1;
  const unsigned long long lmask = (1ull << lane) - 1ull;
  int rankw = 0;
#pragma unroll
  for (int b = 0; b < 16; ++b) {
    const unsigned long long m = __ballot(bin == b);
    if (bin == b) rankw = __popcll(m & lmask);
    if (lane == b) wcnt[w][b] = __popcll(m);
  }
  __syncthreads();
  if (tid < 16) {
    const int tot = wcnt[0][tid] + wcnt[1][tid] + wcnt[2][tid] + wcnt[3][tid];
    bbase[tid] = gbase[tid] + atomicAdd(&gcursor[tid], tot);
  }
  __syncthreads();
  int rank = rankw;
  for (int w2 = 0; w2 < w; ++w2) rank += wcnt[w2][bin];
  const int slot = bbase[bin] + rank;
  perm[slot] = gid;
  len_perm[slot] = len;
  slot_of[gid] = slot;
}

// ---------------------------------------------------------------------------
// one-hot -> char index (byte), written SLOT-indexed: idx_p[t][slot_of[n]].
// 2 rows per wave (float4/lane). Runs after the sort.
// ---------------------------------------------------------------------------
__global__ __launch_bounds__(256) void k_extract(const float* __restrict__ x,
                                                 const int* __restrict__ slot_of,
                                                 unsigned char* __restrict__ idx_p) {
  const int wpair = blockIdx.x * 4 + (threadIdx.x >> 6);
  const int lane  = threadIdx.x & 63;
  const int half  = lane >> 5, sub = lane & 31;
  const long row  = (long)wpair * 2 + half;           // row = n*16 + t
  const f32x4 v = *(const f32x4*)(x + row * NCHARS + sub * 4);
  int loc = -1;
  loc = (v[0] > 0.5f) ? 0 : loc;
  loc = (v[1] > 0.5f) ? 1 : loc;
  loc = (v[2] > 0.5f) ? 2 : loc;
  loc = (v[3] > 0.5f) ? 3 : loc;
  const unsigned long long ball = __ballot(loc >= 0);
  const int w0 = __ffsll((unsigned long long)(ball & 0xffffffffull)) - 1;
  const int w1 = __ffsll((unsigned long long)(ball >> 32)) - 1 + 32;
  const int myv = sub * 4 + loc;
  const int c0 = __shfl(myv, w0);
  const int c1 = __shfl(myv, w1);
  if (lane == 0) {
    const int r0 = wpair * 2, r1 = r0 + 1;
    idx_p[(r0 & 15) * N_WORDS + slot_of[r0 >> 4]] = (unsigned char)c0;
    idx_p[(r1 & 15) * N_WORDS + slot_of[r1 >> 4]] = (unsigned char)c1;
  }
}

// ---------------------------------------------------------------------------
// xproj table xp[dir][char][unit] = float4 gates (i,f,g,o) incl. b_ih+b_hh
// ---------------------------------------------------------------------------
__global__ __launch_bounds__(256) void k_prep(
    const float* __restrict__ Wf, const float* __restrict__ bif, const float* __restrict__ bhf,
    const float* __restrict__ Wb, const float* __restrict__ bib, const float* __restrict__ bhb,
    f32x4* __restrict__ outp) {
  const int gid = blockIdx.x * 256 + threadIdx.x;   // [0, 32768)
  const int u = gid & 127;
  const int c = (gid >> 7) & 127;
  const int d = gid >> 14;
  const float* W  = d ? Wb : Wf;
  const float* bi = d ? bib : bif;
  const float* bh = d ? bhb : bhf;
  f32x4 v;
#pragma unroll
  for (int g = 0; g < 4; ++g) {
    const int gr = g * HIDDEN + u;
    v[g] = W[gr * NCHARS + c] + bi[gr] + bh[gr];
  }
  outp[gid] = v;
}

// ---------------------------------------------------------------------------
// recurrence. Block = 512 threads = 8 waves = ONE 16-slot tile, one dir.
// Wave ug owns units [ug*16, ug*16+16). Runs exactly maxlen(tile) steps
// (slots are length-sorted). Reg cap 128 -> 2 independent blocks/CU.
//   A-frag: lane l reads k = kt*32 + (l>>4)*4 + j (j<4), +16 for j>=4
//   C/D   : lane l, reg r -> row m=(l>>4)*4+r, col n=l&15
// ---------------------------------------------------------------------------
__global__ __launch_bounds__(512, 4) void k_lstm(
    const float* __restrict__ Whh_f, const float* __restrict__ Whh_b,
    const f32x4* __restrict__ xproj, const unsigned char* __restrict__ idx_p,
    const int* __restrict__ perm, const int* __restrict__ len_perm,
    float* __restrict__ out) {
  const int dir = blockIdx.x >> 10;
  const int n0  = (blockIdx.x & 1023) << 4;
  const int ug  = threadIdx.x >> 6;
  const int lane = threadIdx.x & 63;
  const int l15 = lane & 15, q = lane >> 4;
  const float* __restrict__ Whh = dir ? Whh_b : Whh_f;

  // B[k][n] = W_hh[n][k], n = gate-row g*128 + ug*16 + l15
  s16x8 Bf[4][4];
#pragma unroll
  for (int g = 0; g < 4; ++g) {
    const int row = g * HIDDEN + ug * 16 + l15;
#pragma unroll
    for (int kt = 0; kt < 4; ++kt) {
      const int k0 = kt * 32 + q * 4;
      const f32x4 lo = *(const f32x4*)(Whh + row * HIDDEN + k0);
      const f32x4 hi = *(const f32x4*)(Whh + row * HIDDEN + k0 + 16);
      s16x8 f;
      f[0] = f2bf(lo[0]); f[1] = f2bf(lo[1]); f[2] = f2bf(lo[2]); f[3] = f2bf(lo[3]);
      f[4] = f2bf(hi[0]); f[5] = f2bf(hi[1]); f[6] = f2bf(hi[2]); f[7] = f2bf(hi[3]);
      Bf[g][kt] = f;
    }
  }

  __shared__ short hbuf[2][16 * HSTRIDE];
  for (int i = threadIdx.x; i < 16 * HSTRIDE; i += 512) hbuf[0][i] = 0;

  const int wbase = n0 + q * 4;                 // this thread's 4 slots
  const i32x4 lenv = *(const i32x4*)(len_perm + wbase);
  const i32x4 pw   = *(const i32x4*)(perm + wbase);
  int ml = max(max(lenv[0], lenv[1]), max(lenv[2], lenv[3]));
  ml = max(ml, __shfl_xor(ml, 16));
  ml = max(ml, __shfl_xor(ml, 32));
  const int maxlen = ml;

  f32x4 h = (f32x4)0.0f, c = (f32x4)0.0f;
  const int pos = (ug >> 1) * 32 + (l15 >> 2) * 8 + (ug & 1) * 4 + (l15 & 3);
  const int u = ug * 16 + l15;

  u32 cc = *(const u32*)(idx_p + (dir ? (maxlen - 1) : 0) * N_WORDS + wbase);

  __syncthreads();

  for (int t = 0; t < maxlen; ++t) {
    const int t_eff = dir ? (maxlen - 1 - t) : t;
    const short* __restrict__ hr = hbuf[t & 1] + l15 * HSTRIDE;
    short* __restrict__ hw = hbuf[(t & 1) ^ 1];

    // xproj gathers for this step (issued before MFMA)
    f32x4 xpv[4];
#pragma unroll
    for (int r = 0; r < 4; ++r) {
      const int ch = (cc >> (8 * r)) & 255;
      xpv[r] = xproj[(dir << 14) + (ch << 7) + u];
    }
    // prefetch next step's packed char indices
    if (t + 1 < maxlen) {
      const int t2 = dir ? (maxlen - 2 - t) : (t + 1);
      cc = *(const u32*)(idx_p + t2 * N_WORDS + wbase);
    }

    f32x4 acc[4] = {(f32x4)0.0f, (f32x4)0.0f, (f32x4)0.0f, (f32x4)0.0f};
#pragma unroll
    for (int kt = 0; kt < 4; ++kt) {
      const s16x8 a = *(const s16x8*)(hr + kt * 32 + q * 8);
#pragma unroll
      for (int g = 0; g < 4; ++g)
        acc[g] = __builtin_amdgcn_mfma_f32_16x16x32_bf16(a, Bf[g][kt], acc[g], 0, 0, 0);
    }

#pragma unroll
    for (int r = 0; r < 4; ++r) {
      const bool mk = (t_eff < lenv[r]);
      const float gi = fast_sigmoid(acc[0][r] + xpv[r][0]);
      const float gf = fast_sigmoid(acc[1][r] + xpv[r][1]);
      const float gg = fast_tanh   (acc[2][r] + xpv[r][2]);
      const float go = fast_sigmoid(acc[3][r] + xpv[r][3]);
      const float cn = gf * c[r] + gi * gg;
      const float hn = go * fast_tanh(cn);
      c[r] = mk ? cn : c[r];
      h[r] = mk ? hn : h[r];
      hw[(q * 4 + r) * HSTRIDE + pos] = f2bf(h[r]);
    }
    __syncthreads();
  }

#pragma unroll
  for (int r = 0; r < 4; ++r)
    out[(size_t)pw[r] * 256 + dir * HIDDEN + u] = h[r];
}

// ---------------------------------------------------------------------------
extern "C" void kernel_launch(void* const* d_in, const int* in_sizes, int n_in,
                              void* d_out, int out_size, void* d_ws, size_t ws_size,
                              hipStream_t stream) {
  const float* x      = (const float*)d_in[0];
  const int*   lens   = (const int*)d_in[1];
  const float* W_ih_f = (const float*)d_in[2];
  const float* W_hh_f = (const float*)d_in[3];
  const float* b_ih_f = (const float*)d_in[4];
  const float* b_hh_f = (const float*)d_in[5];
  const float* W_ih_b = (const float*)d_in[6];
  const float* W_hh_b = (const float*)d_in[7];
  const float* b_ih_b = (const float*)d_in[8];
  const float* b_hh_b = (const float*)d_in[9];
  float* out = (float*)d_out;

  unsigned char* idx_p = (unsigned char*)d_ws + WS_IDX;
  f32x4* xproj   = (f32x4*)((char*)d_ws + WS_XPROJ);
  int*   perm    = (int*)((char*)d_ws + WS_PERM);
  int*   lenp    = (int*)((char*)d_ws + WS_LEN);
  int*   slot_of = (int*)((char*)d_ws + WS_INV);
  int*   ghist   = (int*)((char*)d_ws + WS_CTRL);
  int*   gbase   = ghist + 16;
  int*   gcursor = ghist + 32;

  hipMemsetAsync((char*)d_ws + WS_CTRL, 0, 192, stream);
  hipLaunchKernelGGL(k_hist, dim3(N_WORDS / 256), dim3(256), 0, stream, lens, ghist);
  hipLaunchKernelGGL(k_scan, dim3(1), dim3(64), 0, stream, ghist, gbase);
  hipLaunchKernelGGL(k_place, dim3(N_WORDS / 256), dim3(256), 0, stream,
                     lens, gbase, gcursor, perm, lenp, slot_of);
  hipLaunchKernelGGL(k_extract, dim3((N_WORDS * TSTEPS) / 8), dim3(256), 0, stream,
                     x, slot_of, idx_p);
  hipLaunchKernelGGL(k_prep, dim3(32768 / 256), dim3(256), 0, stream,
                     W_ih_f, b_ih_f, b_hh_f, W_ih_b, b_ih_b, b_hh_b, xproj);
  hipLaunchKernelGGL(k_lstm, dim3(2048), dim3(512), 0, stream,
                     W_hh_f, W_hh_b, xproj, idx_p, perm, lenp, out);
}

// Round 5
// 111.009 us; speedup vs baseline: 2.6171x; 1.9614x over previous
//
#include <hip/hip_runtime.h>

#define N_WORDS 16384
#define TSTEPS 16
#define NCHARS 128
#define HIDDEN 128
#define HSTRIDE 136   // shorts per LDS row: 16B-aligned, 2-way-bank (free)

typedef float f32x4 __attribute__((ext_vector_type(4)));
typedef short s16x8 __attribute__((ext_vector_type(8)));
typedef int   i32x4 __attribute__((ext_vector_type(4)));
typedef unsigned int u32;

// ws layout (bytes); proven ws_size >= 1.5 MB (R2 used 1.5 MB)
#define WS_IDX    0                        // 256 KB : idx_p bytes [t][slot]
#define WS_XPROJ  (256 * 1024)             // 512 KB : xproj_t f32 [dir][char][gate][unit]
#define WS_PERM   (768 * 1024)             // 64 KB  : perm (slot -> word)
#define WS_LEN    (832 * 1024)             // 64 KB  : len_perm (slot -> len)
#define WS_INV    (896 * 1024)             // 64 KB  : slot_of (word -> slot)
#define WS_CTRL   (960 * 1024)             // 192 B  : ghist[16] | pad | gcursor[16]
#define WS_WFRAG  (1024 * 1024)            // 256 KB : W_hh bf16 MFMA B-fragments

static __device__ __forceinline__ short f2bf(float f) {
  unsigned u = __builtin_bit_cast(unsigned, f);
  u += 0x7FFFu + ((u >> 16) & 1u);
  return (short)(u >> 16);
}
static __device__ __forceinline__ float fast_sigmoid(float x) {
  float e = __builtin_amdgcn_exp2f(x * -1.44269504089f);   // e^-x
  return __builtin_amdgcn_rcpf(1.0f + e);
}
static __device__ __forceinline__ float fast_tanh(float x) {
  float e = __builtin_amdgcn_exp2f(x * 2.88539008178f);    // e^{2x}
  return 1.0f - 2.0f * __builtin_amdgcn_rcpf(1.0f + e);
}

// ---------------------------------------------------------------------------
// histogram of lengths, DESCENDING bins: bin = 16 - len (bin 0 = len 16)
// ---------------------------------------------------------------------------
__global__ __launch_bounds__(256) void k_hist(const int* __restrict__ lengths,
                                              int* __restrict__ ghist) {
  __shared__ int lh[16];
  if (threadIdx.x < 16) lh[threadIdx.x] = 0;
  __syncthreads();
  const int len = lengths[blockIdx.x * 256 + threadIdx.x];
  atomicAdd(&lh[16 - len], 1);
  __syncthreads();
  if (threadIdx.x < 16) atomicAdd(&ghist[threadIdx.x], lh[threadIdx.x]);
}

// ---------------------------------------------------------------------------
// place with inline exclusive scan of ghist (no separate scan kernel).
// Any within-bin permutation yields bit-identical per-word output (rows of
// the MFMA are independent; out is scattered by word id) -> deterministic.
// ---------------------------------------------------------------------------
__global__ __launch_bounds__(256) void k_place(const int* __restrict__ lengths,
                                               const int* __restrict__ ghist,
                                               int* __restrict__ gcursor,
                                               int* __restrict__ perm,
                                               int* __restrict__ len_perm,
                                               int* __restrict__ slot_of) {
  __shared__ int wcnt[4][16];
  __shared__ int bbase[16];
  const int tid = threadIdx.x, w = tid >> 6, lane = tid & 63;
  const int gid = blockIdx.x * 256 + tid;
  const int len = lengths[gid], bin = 16 - len;
  const unsigned long long lmask = (1ull << lane) - 1ull;
  int rankw = 0;
#pragma unroll
  for (int b = 0; b < 16; ++b) {
    const unsigned long long m = __ballot(bin == b);
    if (bin == b) rankw = __popcll(m & lmask);
    if (lane == b) wcnt[w][b] = __popcll(m);
  }
  __syncthreads();
  if (tid < 16) {
    int s = 0;
    for (int b = 0; b < tid; ++b) s += ghist[b];      // exclusive scan
    const int tot = wcnt[0][tid] + wcnt[1][tid] + wcnt[2][tid] + wcnt[3][tid];
    bbase[tid] = s + atomicAdd(&gcursor[tid], tot);
  }
  __syncthreads();
  int rank = rankw;
  for (int w2 = 0; w2 < w; ++w2) rank += wcnt[w2][bin];
  const int slot = bbase[bin] + rank;
  perm[slot] = gid;
  len_perm[slot] = len;
  slot_of[gid] = slot;
}

// ---------------------------------------------------------------------------
// one-hot -> char byte, slot-indexed, SKIPPING padded rows (t >= len).
// 2 rows per wave (one per 32-lane half).
// ---------------------------------------------------------------------------
__global__ __launch_bounds__(256) void k_extract(const float* __restrict__ x,
                                                 const int* __restrict__ lengths,
                                                 const int* __restrict__ slot_of,
                                                 unsigned char* __restrict__ idx_p) {
  const int wpair = blockIdx.x * 4 + (threadIdx.x >> 6);
  const int lane  = threadIdx.x & 63;
  const int half  = lane >> 5, sub = lane & 31;
  const int row   = wpair * 2 + half;                 // row = n*16 + t
  const int n = row >> 4, t = row & 15;
  const int len = lengths[n];
  int myv = -1;
  if (t < len) {
    const f32x4 v = *(const f32x4*)(x + (size_t)row * NCHARS + sub * 4);
    int loc = -1;
    loc = (v[0] > 0.5f) ? 0 : loc;
    loc = (v[1] > 0.5f) ? 1 : loc;
    loc = (v[2] > 0.5f) ? 2 : loc;
    loc = (v[3] > 0.5f) ? 3 : loc;
    if (loc >= 0) myv = sub * 4 + loc;
  }
  const unsigned long long ball = __ballot(myv >= 0);
  const unsigned long long mym = half ? (ball >> 32) : (ball & 0xffffffffull);
  const int wn = __ffsll(mym) - 1 + (half << 5);      // winner lane (valid iff t<len)
  const int c = __shfl(myv, wn);                      // executed by all lanes
  if (sub == 0 && t < len)
    idx_p[t * N_WORDS + slot_of[n]] = (unsigned char)c;
}

// ---------------------------------------------------------------------------
// fused prep: blocks [0,512) build xproj_t[dir][char][gate][unit] (f32, incl.
// b_ih+b_hh); blocks [512,576) convert W_hh to bf16 MFMA B-fragments laid out
// [dir][wave][frag][lane] so the LSTM prologue is 16 coalesced dwordx4 loads.
// ---------------------------------------------------------------------------
__global__ __launch_bounds__(256) void k_prepw(
    const float* __restrict__ Wihf, const float* __restrict__ bif, const float* __restrict__ bhf,
    const float* __restrict__ Wihb, const float* __restrict__ bib, const float* __restrict__ bhb,
    const float* __restrict__ Whhf, const float* __restrict__ Whhb,
    float* __restrict__ xp, s16x8* __restrict__ wfrag) {
  if (blockIdx.x < 512) {
    const int gid = blockIdx.x * 256 + threadIdx.x;   // [0, 131072)
    const int u = gid & 127;
    const int g = (gid >> 7) & 3;
    const int c = (gid >> 9) & 127;
    const int d = gid >> 16;
    const float* W  = d ? Wihb : Wihf;
    const float* bi = d ? bib : bif;
    const float* bh = d ? bhb : bhf;
    const int row = g * HIDDEN + u;
    xp[gid] = W[row * NCHARS + c] + bi[row] + bh[row];
  } else {
    const int gid = (blockIdx.x - 512) * 256 + threadIdx.x;  // [0, 16384)
    const int f    = gid & 15;          // frag: g = f>>2, kt = f&3
    const int lane = (gid >> 4) & 63;
    const int ug   = (gid >> 10) & 7;
    const int d    = gid >> 13;
    const float* W = d ? Whhb : Whhf;
    const int l15 = lane & 15, q = lane >> 4;
    const int row = (f >> 2) * HIDDEN + ug * 16 + l15;
    const int k0  = (f & 3) * 32 + q * 4;
    const f32x4 lo = *(const f32x4*)(W + row * HIDDEN + k0);
    const f32x4 hi = *(const f32x4*)(W + row * HIDDEN + k0 + 16);
    s16x8 o;
    o[0] = f2bf(lo[0]); o[1] = f2bf(lo[1]); o[2] = f2bf(lo[2]); o[3] = f2bf(lo[3]);
    o[4] = f2bf(hi[0]); o[5] = f2bf(hi[1]); o[6] = f2bf(hi[2]); o[7] = f2bf(hi[3]);
    wfrag[((d * 8 + ug) * 16 + f) * 64 + lane] = o;
  }
}

// ---------------------------------------------------------------------------
// recurrence, PERSISTENT blocks: 512 blocks x 512 thr; blocks [0,256)=dir0,
// [256,512)=dir1. Block b handles 4 tiles: ranks {db, 511-db, 512+db, 1023-db}
// (descending-length sort -> constant per-block work, LPT-balanced).
// W_hh frags loaded once per block into 64 AGPRs/lane. xproj gathers load
// DIRECTLY into the MFMA C-operand (acc init), no epilogue adds.
//   A-frag: lane l reads k = kt*32 + (l>>4)*4 + j (j<4), +16 for j>=4
//   C/D   : lane l, reg r -> row m=(l>>4)*4+r, col n=l&15
// ---------------------------------------------------------------------------
__global__ __launch_bounds__(512, 4) void k_lstm(
    const float* __restrict__ xp, const unsigned char* __restrict__ idx_p,
    const int* __restrict__ perm, const int* __restrict__ len_perm,
    const s16x8* __restrict__ wfrag, float* __restrict__ out) {
  const int dir = blockIdx.x >> 8;
  const int db  = blockIdx.x & 255;
  const int ug  = threadIdx.x >> 6;
  const int lane = threadIdx.x & 63;
  const int l15 = lane & 15, q = lane >> 4;
  const int u = ug * 16 + l15;

  s16x8 Bf[16];                                  // [g*4+kt], lives in AGPRs
  const s16x8* wb = wfrag + (dir * 8 + ug) * (16 * 64) + lane;
#pragma unroll
  for (int f = 0; f < 16; ++f) Bf[f] = wb[f * 64];

  __shared__ short hbuf[2][16 * HSTRIDE];
  const float* __restrict__ xpd = xp + (dir << 16);
  const int pos = (ug >> 1) * 32 + (l15 >> 2) * 8 + (ug & 1) * 4 + (l15 & 3);

#pragma unroll 1
  for (int p = 0; p < 4; ++p) {
    const int rank = (p == 0) ? db : (p == 1) ? (511 - db)
                   : (p == 2) ? (512 + db) : (1023 - db);
    const int n0 = rank << 4;
    for (int i = threadIdx.x; i < 16 * HSTRIDE; i += 512) hbuf[0][i] = 0;
    const int wbase = n0 + q * 4;
    const i32x4 lenv = *(const i32x4*)(len_perm + wbase);
    const i32x4 pw   = *(const i32x4*)(perm + wbase);
    const int maxlen = len_perm[n0];             // slot n0 = longest in tile
    f32x4 h = (f32x4)0.0f, cs = (f32x4)0.0f;
    u32 cc = *(const u32*)(idx_p + (dir ? (maxlen - 1) : 0) * N_WORDS + wbase);
    __syncthreads();

#pragma unroll 1
    for (int t = 0; t < maxlen; ++t) {
      const int t_eff = dir ? (maxlen - 1 - t) : t;
      const short* __restrict__ hr = hbuf[t & 1] + l15 * HSTRIDE;
      short* __restrict__ hw = hbuf[(t & 1) ^ 1];

      // gather xproj straight into the MFMA C operand
      f32x4 acc[4];
#pragma unroll
      for (int r = 0; r < 4; ++r) {
        const int ch = (cc >> (8 * r)) & 127;
        const float* pa = xpd + (ch << 9) + u;
        acc[0][r] = pa[0];
        acc[1][r] = pa[128];
        acc[2][r] = pa[256];
        acc[3][r] = pa[384];
      }
      if (t + 1 < maxlen) {
        const int t2 = dir ? (maxlen - 2 - t) : (t + 1);
        cc = *(const u32*)(idx_p + t2 * N_WORDS + wbase);
      }

#pragma unroll
      for (int kt = 0; kt < 4; ++kt) {
        const s16x8 a = *(const s16x8*)(hr + kt * 32 + q * 8);
#pragma unroll
        for (int g = 0; g < 4; ++g)
          acc[g] = __builtin_amdgcn_mfma_f32_16x16x32_bf16(a, Bf[g * 4 + kt], acc[g], 0, 0, 0);
      }

      const bool dowr = (t + 1 < maxlen);
#pragma unroll
      for (int r = 0; r < 4; ++r) {
        const bool mk = (t_eff < lenv[r]);
        const float gi = fast_sigmoid(acc[0][r]);
        const float gf = fast_sigmoid(acc[1][r]);
        const float gg = fast_tanh   (acc[2][r]);
        const float go = fast_sigmoid(acc[3][r]);
        const float cn = gf * cs[r] + gi * gg;
        const float hn = go * fast_tanh(cn);
        cs[r] = mk ? cn : cs[r];
        h[r]  = mk ? hn : h[r];
        if (dowr) hw[(q * 4 + r) * HSTRIDE + pos] = f2bf(h[r]);
      }
      __syncthreads();
    }

#pragma unroll
    for (int r = 0; r < 4; ++r)
      out[(size_t)pw[r] * 256 + dir * HIDDEN + u] = h[r];
  }
}

// ---------------------------------------------------------------------------
extern "C" void kernel_launch(void* const* d_in, const int* in_sizes, int n_in,
                              void* d_out, int out_size, void* d_ws, size_t ws_size,
                              hipStream_t stream) {
  const float* x      = (const float*)d_in[0];
  const int*   lens   = (const int*)d_in[1];
  const float* W_ih_f = (const float*)d_in[2];
  const float* W_hh_f = (const float*)d_in[3];
  const float* b_ih_f = (const float*)d_in[4];
  const float* b_hh_f = (const float*)d_in[5];
  const float* W_ih_b = (const float*)d_in[6];
  const float* W_hh_b = (const float*)d_in[7];
  const float* b_ih_b = (const float*)d_in[8];
  const float* b_hh_b = (const float*)d_in[9];
  float* out = (float*)d_out;

  unsigned char* idx_p = (unsigned char*)d_ws + WS_IDX;
  float* xp      = (float*)((char*)d_ws + WS_XPROJ);
  int*   perm    = (int*)((char*)d_ws + WS_PERM);
  int*   lenp    = (int*)((char*)d_ws + WS_LEN);
  int*   slot_of = (int*)((char*)d_ws + WS_INV);
  int*   ghist   = (int*)((char*)d_ws + WS_CTRL);
  int*   gcursor = ghist + 32;
  s16x8* wfrag   = (s16x8*)((char*)d_ws + WS_WFRAG);

  hipMemsetAsync((char*)d_ws + WS_CTRL, 0, 192, stream);
  hipLaunchKernelGGL(k_hist, dim3(N_WORDS / 256), dim3(256), 0, stream, lens, ghist);
  hipLaunchKernelGGL(k_place, dim3(N_WORDS / 256), dim3(256), 0, stream,
                     lens, ghist, gcursor, perm, lenp, slot_of);
  hipLaunchKernelGGL(k_extract, dim3((N_WORDS * TSTEPS) / 8), dim3(256), 0, stream,
                     x, lens, slot_of, idx_p);
  hipLaunchKernelGGL(k_prepw, dim3(576), dim3(256), 0, stream,
                     W_ih_f, b_ih_f, b_hh_f, W_ih_b, b_ih_b, b_hh_b,
                     W_hh_f, W_hh_b, xp, wfrag);
  hipLaunchKernelGGL(k_lstm, dim3(512), dim3(512), 0, stream,
                     xp, idx_p, perm, lenp, wfrag, out);
}